// Round 14
// baseline (261.101 us; speedup 1.0000x reference)
//
#include <hip/hip_runtime.h>
#include <hip/hip_bf16.h>
#include <math.h>

typedef __attribute__((ext_vector_type(4))) float f32x4;
typedef __attribute__((ext_vector_type(8))) short short8;

#define DMODEL 768
#define NH 12
#define HD 64
#define DFF 3072
#define KVB 64
#define NSPLIT 2
#define QH 2
#define NP 1040   // padded Vt row stride

struct FalseC { static constexpr bool v = false; };
struct TrueC  { static constexpr bool v = true;  };

__device__ __forceinline__ short f2bf(float f) {
    union { float f; unsigned int u; } c; c.f = f;
    unsigned int r = c.u + 0x7FFFu + ((c.u >> 16) & 1u);
    return (short)(r >> 16);
}

__device__ __forceinline__ float bf2f(short s) {
    union { unsigned int u; float f; } c; c.u = ((unsigned int)(unsigned short)s) << 16;
    return c.f;
}

__device__ __forceinline__ void gload16(const void* g, void* l) {
    __builtin_amdgcn_global_load_lds((const __attribute__((address_space(1))) void*)g,
                                     (__attribute__((address_space(3))) void*)l, 16, 0, 0);
}

// bijective XCD-chunking swizzle (m204)
__device__ __forceinline__ int xcd_swz(int o, int nwg) {
    int q = nwg >> 3, r = nwg & 7, x = o & 7, i = o >> 3;
    return (x < r ? x * (q + 1) : r * (q + 1) + (x - r) * q) + i;
}

// ---------------- batched weight transpose + cast (all 6 weights in one launch) ----------------
__global__ __launch_bounds__(256) void transpose_all(
        const float* __restrict__ wq, const float* __restrict__ wk, const float* __restrict__ wv,
        const float* __restrict__ wo, const float* __restrict__ w1, const float* __restrict__ w2,
        short* __restrict__ wt_qkv, short* __restrict__ wt_o,
        short* __restrict__ wt_1, short* __restrict__ wt_2) {
    __shared__ float tile[32][33];
    int bid = blockIdx.x;
    const float* src; short* dst; int K, Nn, nx;
    if (bid < 2304) {
        int s = bid / 576; bid -= s * 576;
        src = (s == 0) ? wq : (s == 1) ? wk : (s == 2) ? wv : wo;
        dst = (s < 3) ? (wt_qkv + (size_t)s * 768 * 768) : wt_o;
        K = 768; Nn = 768; nx = 24;
    } else if (bid < 4608) {
        bid -= 2304; src = w1; dst = wt_1; K = 768; Nn = 3072; nx = 96;
    } else {
        bid -= 4608; src = w2; dst = wt_2; K = 3072; Nn = 768; nx = 24;
    }
    const int n0 = (bid % nx) * 32, k0 = (bid / nx) * 32;
    const int tx = threadIdx.x & 31, ty = threadIdx.x >> 5;
    #pragma unroll
    for (int i = ty; i < 32; i += 8) {
        int k = k0 + i, n = n0 + tx;
        tile[i][tx] = (k < K && n < Nn) ? src[(size_t)k * Nn + n] : 0.f;
    }
    __syncthreads();
    #pragma unroll
    for (int i = ty; i < 32; i += 8) {
        int n = n0 + i, k = k0 + tx;
        if (n < Nn && k < K) dst[(size_t)n * K + k] = f2bf(tile[tx][i]);
    }
}

__global__ void concat_bias(const float* __restrict__ bq, const float* __restrict__ bk,
                            const float* __restrict__ bv, float* __restrict__ out) {
    int i = blockIdx.x * 256 + threadIdx.x;
    if (i < 2304) out[i] = (i < 768) ? bq[i] : (i < 1536 ? bk[i - 768] : bv[i - 1536]);
}

// ---------------- row LayerNorm over D=768, out bf16 ----------------
__global__ __launch_bounds__(256) void ln_rows(const float* __restrict__ x, const float* __restrict__ g,
                                               const float* __restrict__ bb, short* __restrict__ out, int M) {
    __shared__ float red[8];
    const int row = blockIdx.x;
    const int tid = threadIdx.x;
    const float* xr = x + (size_t)row * DMODEL;
    float v[3];
    #pragma unroll
    for (int j = 0; j < 3; j++) v[j] = xr[tid + j * 256];
    float s = v[0] + v[1] + v[2];
    #pragma unroll
    for (int mk = 32; mk; mk >>= 1) s += __shfl_xor(s, mk);
    if ((tid & 63) == 0) red[tid >> 6] = s;
    __syncthreads();
    const float mean = (red[0] + red[1] + red[2] + red[3]) * (1.0f / 768.0f);
    float sq = 0.f;
    #pragma unroll
    for (int j = 0; j < 3; j++) { float d = v[j] - mean; sq += d * d; }
    #pragma unroll
    for (int mk = 32; mk; mk >>= 1) sq += __shfl_xor(sq, mk);
    if ((tid & 63) == 0) red[4 + (tid >> 6)] = sq;
    __syncthreads();
    const float var = (red[4] + red[5] + red[6] + red[7]) * (1.0f / 768.0f);
    const float rstd = rsqrtf(var + 1e-5f);
    short* orow = out + (size_t)row * DMODEL;
    #pragma unroll
    for (int j = 0; j < 3; j++) {
        int col = tid + j * 256;
        orow[col] = f2bf((v[j] - mean) * rstd * g[col] + bb[col]);
    }
}

// ---------------- QKV GEMM with fused qk-norm + V-transpose epilogue ----------------
__global__ __launch_bounds__(256) void gemm_qkv(const short* __restrict__ A, const short* __restrict__ Bt,
        const float* __restrict__ bias,
        const float* __restrict__ qg, const float* __restrict__ qb2,
        const float* __restrict__ kg, const float* __restrict__ kb2,
        short* __restrict__ Qb, short* __restrict__ Kb, short* __restrict__ Vtp,
        int M, int B, int Nseq) {
    __shared__ short As[64 * 64];
    __shared__ short Bs[128 * 64];
    const int nbx = 18, nby = (M + 63) / 64;
    const int sid = xcd_swz(blockIdx.x, nbx * nby);
    const int n0 = (sid % nbx) * 128, m0 = (sid / nbx) * 64;
    const int tid = threadIdx.x, w = tid >> 6, lane = tid & 63, g = lane >> 4, cl = lane & 15;
    const int wm = w >> 1, wn = w & 1;
    f32x4 acc[2][4];
    #pragma unroll
    for (int a = 0; a < 2; a++)
        #pragma unroll
        for (int b2 = 0; b2 < 4; b2++) acc[a][b2] = (f32x4){0.f, 0.f, 0.f, 0.f};
    for (int kk = 0; kk < 768; kk += 64) {
        #pragma unroll
        for (int c = 0; c < 1536; c += 256) {
            int ci = c + tid;
            if (ci < 512) {
                int row = ci >> 3, p = ci & 7;
                int arow = m0 + row; if (arow >= M) arow = M - 1;
                gload16(A + (size_t)arow * 768 + kk + ((p ^ (row & 7)) << 3), &As[ci * 8]);
            } else {
                int c2 = ci - 512;
                int row = c2 >> 3, p = c2 & 7;
                gload16(Bt + (size_t)(n0 + row) * 768 + kk + ((p ^ (row & 7)) << 3), &Bs[c2 * 8]);
            }
        }
        __syncthreads();
        #pragma unroll
        for (int kh = 0; kh < 2; ++kh) {
            short8 af[2], bf[4];
            #pragma unroll
            for (int mi = 0; mi < 2; mi++) {
                int ra = wm * 32 + mi * 16 + cl;
                af[mi] = *(const short8*)&As[ra * 64 + ((((kh << 2) + g) ^ (ra & 7)) << 3)];
            }
            #pragma unroll
            for (int ni = 0; ni < 4; ni++) {
                int rb = wn * 64 + ni * 16 + cl;
                bf[ni] = *(const short8*)&Bs[rb * 64 + ((((kh << 2) + g) ^ (rb & 7)) << 3)];
            }
            #pragma unroll
            for (int mi = 0; mi < 2; mi++)
                #pragma unroll
                for (int ni = 0; ni < 4; ni++)
                    acc[mi][ni] = __builtin_amdgcn_mfma_f32_16x16x32_bf16(af[mi], bf[ni], acc[mi][ni], 0, 0, 0);
        }
        __syncthreads();
    }
    const int t = n0 / 768;
    const int h = (n0 - t * 768) / 64 + wn;
    const int b0 = m0 / Nseq, bnd = (b0 + 1) * Nseq;
    float bi[4];
    #pragma unroll
    for (int ni = 0; ni < 4; ni++) bi[ni] = bias[n0 + wn * 64 + ni * 16 + cl];
    if (t < 2) {
        const float* gp = (t == 0) ? qg : kg;
        const float* bp = (t == 0) ? qb2 : kb2;
        float gv[4], bv[4];
        #pragma unroll
        for (int ni = 0; ni < 4; ni++) { gv[ni] = gp[ni * 16 + cl]; bv[ni] = bp[ni * 16 + cl]; }
        short* out = (t == 0) ? Qb : Kb;
        #pragma unroll
        for (int mi = 0; mi < 2; mi++)
            #pragma unroll
            for (int r = 0; r < 4; r++) {
                int row = m0 + wm * 32 + mi * 16 + 4 * g + r;
                float v0 = acc[mi][0][r] + bi[0];
                float v1 = acc[mi][1][r] + bi[1];
                float v2 = acc[mi][2][r] + bi[2];
                float v3 = acc[mi][3][r] + bi[3];
                float sx = v0 + v1 + v2 + v3;
                float sxx = v0 * v0 + v1 * v1 + v2 * v2 + v3 * v3;
                #pragma unroll
                for (int mk = 8; mk; mk >>= 1) { sx += __shfl_xor(sx, mk); sxx += __shfl_xor(sxx, mk); }
                float mean = sx * (1.0f / 64.0f);
                float var = sxx * (1.0f / 64.0f) - mean * mean;
                float rstd = rsqrtf(var + 1e-5f);
                if (row < M) {
                    int bb = (row >= bnd) ? b0 + 1 : b0;
                    int n = row - bb * Nseq;
                    size_t base = (((size_t)bb * NH + h) * Nseq + n) * HD + cl;
                    out[base + 0]  = f2bf(fmaf((v0 - mean) * rstd, gv[0], bv[0]));
                    out[base + 16] = f2bf(fmaf((v1 - mean) * rstd, gv[1], bv[1]));
                    out[base + 32] = f2bf(fmaf((v2 - mean) * rstd, gv[2], bv[2]));
                    out[base + 48] = f2bf(fmaf((v3 - mean) * rstd, gv[3], bv[3]));
                }
            }
    } else {
        #pragma unroll
        for (int mi = 0; mi < 2; mi++)
            #pragma unroll
            for (int r = 0; r < 4; r++) {
                int row = m0 + wm * 32 + mi * 16 + 4 * g + r;
                if (row < M) {
                    int bb = (row >= bnd) ? b0 + 1 : b0;
                    int n = row - bb * Nseq;
                    size_t vb2 = ((size_t)bb * NH + h) * HD + cl;
                    #pragma unroll
                    for (int ni = 0; ni < 4; ni++)
                        Vtp[(vb2 + ni * 16) * NP + n] = f2bf(acc[mi][ni][r] + bi[ni]);
                }
            }
    }
}

// ---------------- GEMM (R7 single-buffer BK=64): C = A * Bt^T + epilogue ----------------
template<int EPI, int BM, int BN>
__global__ __launch_bounds__(256) void gemm_bt(const short* __restrict__ A, const short* __restrict__ Bt,
        const float* __restrict__ bias, const float* __restrict__ res, void* __restrict__ Cv,
        int M, int Nn, int K) {
    constexpr int RM = BM / 32, RN = BN / 32;
    __shared__ short As[BM * 64];
    __shared__ short Bs[BN * 64];
    const int nbx = Nn / BN, nby = (M + BM - 1) / BM;
    const int sid = xcd_swz(blockIdx.x, nbx * nby);
    const int n0 = (sid % nbx) * BN, m0 = (sid / nbx) * BM;
    const int tid = threadIdx.x, w = tid >> 6, lane = tid & 63, g = lane >> 4, cl = lane & 15;
    const int wm = w >> 1, wn = w & 1;
    f32x4 acc[RM][RN];
    #pragma unroll
    for (int a = 0; a < RM; a++)
        #pragma unroll
        for (int b2 = 0; b2 < RN; b2++) acc[a][b2] = (f32x4){0.f, 0.f, 0.f, 0.f};
    constexpr int CHA = BM * 8, CHT = (BM + BN) * 8;
    for (int kk = 0; kk < K; kk += 64) {
        #pragma unroll
        for (int c = 0; c < CHT; c += 256) {
            int ci = c + tid;
            if (ci < CHA) {
                int row = ci >> 3, p = ci & 7;
                int arow = m0 + row; if (arow >= M) arow = M - 1;
                gload16(A + (size_t)arow * K + kk + ((p ^ (row & 7)) << 3), &As[ci * 8]);
            } else {
                int c2 = ci - CHA;
                int row = c2 >> 3, p = c2 & 7;
                gload16(Bt + (size_t)(n0 + row) * K + kk + ((p ^ (row & 7)) << 3), &Bs[c2 * 8]);
            }
        }
        __syncthreads();
        #pragma unroll
        for (int kh = 0; kh < 2; ++kh) {
            short8 af[RM], bf[RN];
            #pragma unroll
            for (int mi = 0; mi < RM; mi++) {
                int ra = wm * (BM / 2) + mi * 16 + cl;
                af[mi] = *(const short8*)&As[ra * 64 + ((((kh << 2) + g) ^ (ra & 7)) << 3)];
            }
            #pragma unroll
            for (int ni = 0; ni < RN; ni++) {
                int rb = wn * (BN / 2) + ni * 16 + cl;
                bf[ni] = *(const short8*)&Bs[rb * 64 + ((((kh << 2) + g) ^ (rb & 7)) << 3)];
            }
            #pragma unroll
            for (int mi = 0; mi < RM; mi++)
                #pragma unroll
                for (int ni = 0; ni < RN; ni++)
                    acc[mi][ni] = __builtin_amdgcn_mfma_f32_16x16x32_bf16(af[mi], bf[ni], acc[mi][ni], 0, 0, 0);
        }
        __syncthreads();
    }
    #pragma unroll
    for (int ni = 0; ni < RN; ++ni) {
        int col = n0 + wn * (BN / 2) + ni * 16 + cl;
        float bi = bias[col];
        #pragma unroll
        for (int mi = 0; mi < RM; ++mi) {
            int rb = m0 + wm * (BM / 2) + mi * 16 + 4 * g;
            #pragma unroll
            for (int r = 0; r < 4; ++r) {
                int row = rb + r;
                if (row < M) {
                    float vv = acc[mi][ni][r] + bi;
                    if (EPI == 1) {
                        vv += res[(size_t)row * Nn + col];
                        ((float*)Cv)[(size_t)row * Nn + col] = vv;
                    } else {
                        float ge = 0.5f * vv * (1.0f + erff(vv * 0.70710678118654752f));
                        ((short*)Cv)[(size_t)row * Nn + col] = f2bf(ge);
                    }
                }
            }
        }
    }
}

// ---------------- flash attention v10: in-register P redistribution (no Pl LDS), 4 blk/CU ----
// After swapped QK^T lane(g,cl) holds P[k=16qt2+4g+i][q=cl]. PV A-frag needs P[q=cl][8g'+j]:
// pure lane-bit-4/5 exchange (q=cl preserved): shfl_xor 32/16 + selects. LDS = Vbuf+Rs ~33KB.
__global__ __launch_bounds__(256, 4) void attn_kernel(
        const short* __restrict__ Qb, const short* __restrict__ Kb, const short* __restrict__ Vt,
        const float* __restrict__ pos, const float* __restrict__ psz, const int* __restrict__ nregp,
        short* __restrict__ opart, float* __restrict__ ppart, int B, int Nn, int nwg) {
    __shared__ short Vbuf[2][QH][4096];   // per head: [64 d][8 slots of 8 kv], slot^=(d&7)
    __shared__ float Rs[4][QH][16];
    const int nqt = (Nn + 63) >> 6;
    const int sid = xcd_swz(blockIdx.x, nwg);
    const int qt = sid % nqt;
    const int rem = sid / nqt;
    const int nyy = (NH / QH) * NSPLIT;
    const int yy = rem % nyy;
    const int b = rem / nyy;
    const int h0 = (yy / NSPLIT) * QH, sp = yy % NSPLIT;
    const int tid = threadIdx.x, w = tid >> 6, lane = tid & 63, g = lane >> 4, cl = lane & 15;
    const int nreg1 = 1 + nregp[0];
    const float inv_ps = 1.0f / fmaxf(psz[b], 1e-6f);
    const float sc2 = 0.125f * 1.4426950408889634f;
    const size_t bq = (size_t)b * Nn;
    const float2* __restrict__ pos2 = (const float2*)pos;
    const int q0 = qt * 64 + w * 16;

    size_t bh[QH], vb[QH];
    short8 qa[QH][2];
    float sP[QH];
    int qr = q0 + cl; if (qr > Nn - 1) qr = Nn - 1;
    const float2 qp = pos2[bq + qr];
    const float keepq = (qr < nreg1) ? 0.f : 1.f;
    #pragma unroll
    for (int hh = 0; hh < QH; hh++) {
        int h = h0 + hh;
        bh[hh] = ((size_t)b * NH + h) * (size_t)Nn;
        vb[hh] = ((size_t)b * NH + h) * (size_t)(HD * NP);
        float slope = (h < 8) ? exp2f(-(float)(h + 1)) : exp2f(-0.5f - (float)(h - 8));
        sP[hh] = slope * inv_ps * 1.4426950408889634f * keepq;
        const short* qptr = Qb + (bh[hh] + qr) * HD;
        qa[hh][0] = *(const short8*)(qptr + 8 * g);
        qa[hh][1] = *(const short8*)(qptr + 32 + 8 * g);
    }

    int qi[4];
    #pragma unroll
    for (int i = 0; i < 4; i++) qi[i] = q0 + 4 * g + i;

    f32x4 o[QH][4];
    float psum[QH] = {0.f, 0.f};
    #pragma unroll
    for (int hh = 0; hh < QH; hh++)
        #pragma unroll
        for (int c2 = 0; c2 < 4; c2++) o[hh][c2] = (f32x4){0.f, 0.f, 0.f, 0.f};

    const int ktiles = (Nn + KVB - 1) / KVB;
    const int tps = (ktiles + NSPLIT - 1) / NSPLIT;
    const int t0 = sp * tps, t1 = min(ktiles, t0 + tps);

    auto stage = [&](int buf, int kt) {
        const int kv0 = kt * KVB;
        #pragma unroll
        for (int it = 0; it < 2 * QH; ++it) {
            int idx = it * 256 + tid;
            int hh = idx >> 9, rm = idx & 511;
            int d = rm >> 3, slot = rm & 7;
            int kvs = kv0 + ((slot ^ (d & 7)) << 3);
            gload16(Vt + vb[hh] + (size_t)d * NP + kvs, &Vbuf[buf][hh][rm * 8]);
        }
    };

    // redistribute one packed pair: A (quarter 2ks), Bv (quarter 2ks+1) -> vLo (VGPR0/1 slot),
    // vHi (VGPR2/3 slot). Derivation: see header comment.
    auto redist = [&](unsigned A, unsigned Bv, unsigned& vLo, unsigned& vHi) {
        unsigned As32 = (unsigned)__shfl_xor((int)A, 32);
        unsigned Bs32 = (unsigned)__shfl_xor((int)Bv, 32);
        unsigned d0 = (lane < 32) ? A : Bs32;
        unsigned d1 = (lane < 32) ? As32 : Bv;
        unsigned d1x = (unsigned)__shfl_xor((int)d1, 16);
        unsigned d0x = (unsigned)__shfl_xor((int)d0, 16);
        vLo = (lane & 16) ? d1x : d0;
        vHi = (lane & 16) ? d1 : d0x;
    };

    stage(0, t0);
    int cur = 0;
    for (int kt = t0; kt < t1; ++kt) {
        const int kv0 = kt * KVB;
        __syncthreads();                 // drains stage(kt)
        if (kt + 1 < t1) stage(cur ^ 1, kt + 1);

        // ---- swapped QK^T per 16-k quarter; returns packed bf16 pairs per head ----
        auto qbody = [&](int qt2, unsigned (&outp)[2][2], auto mc, auto tc) {
            constexpr bool KMASK = decltype(mc)::v;
            constexpr bool TAIL  = decltype(tc)::v;
            const int kbase = kv0 + qt2 * 16;
            int krow = kbase + cl;
            if (TAIL) krow = min(krow, Nn - 1);
            const short* kp0 = Kb + (bh[0] + krow) * HD;
            const short* kp1 = Kb + (bh[1] + krow) * HD;
            const short8 k00 = *(const short8*)(kp0 + 8 * g);
            const short8 k01 = *(const short8*)(kp0 + 32 + 8 * g);
            const short8 k10 = *(const short8*)(kp1 + 8 * g);
            const short8 k11 = *(const short8*)(kp1 + 32 + 8 * g);
            f32x4 s0 = __builtin_amdgcn_mfma_f32_16x16x32_bf16(k00, qa[0][0], (f32x4){0.f,0.f,0.f,0.f}, 0, 0, 0);
            s0 = __builtin_amdgcn_mfma_f32_16x16x32_bf16(k01, qa[0][1], s0, 0, 0, 0);
            f32x4 s1 = __builtin_amdgcn_mfma_f32_16x16x32_bf16(k10, qa[1][0], (f32x4){0.f,0.f,0.f,0.f}, 0, 0, 0);
            s1 = __builtin_amdgcn_mfma_f32_16x16x32_bf16(k11, qa[1][1], s1, 0, 0, 0);
            const int kb4 = kbase + 4 * g;
            float p0v[4], p1v[4];
            #pragma unroll
            for (int i = 0; i < 4; i++) {
                int ki = kb4 + i;
                int kic = TAIL ? min(ki, Nn - 1) : ki;
                float2 kp2 = pos2[bq + kic];
                float dx = qp.x - kp2.x, dy = qp.y - kp2.y;
                float dist = sqrtf(fmaf(dx, dx, dy * dy));
                if (KMASK) dist *= (ki < nreg1) ? 0.f : 1.f;
                float e0 = fmaf(s0[i], sc2, -12.0f);
                e0 = fmaf(-sP[0], dist, e0);
                float p0 = exp2f(e0);
                float e1 = fmaf(s1[i], sc2, -12.0f);
                e1 = fmaf(-sP[1], dist, e1);
                float p1 = exp2f(e1);
                if (TAIL) { bool vl = ki < Nn; p0 = vl ? p0 : 0.f; p1 = vl ? p1 : 0.f; }
                psum[0] += p0; psum[1] += p1;
                p0v[i] = p0; p1v[i] = p1;
            }
            asm("v_cvt_pk_bf16_f32 %0, %1, %2" : "=v"(outp[0][0]) : "v"(p0v[0]), "v"(p0v[1]));
            asm("v_cvt_pk_bf16_f32 %0, %1, %2" : "=v"(outp[0][1]) : "v"(p0v[2]), "v"(p0v[3]));
            asm("v_cvt_pk_bf16_f32 %0, %1, %2" : "=v"(outp[1][0]) : "v"(p1v[0]), "v"(p1v[1]));
            asm("v_cvt_pk_bf16_f32 %0, %1, %2" : "=v"(outp[1][1]) : "v"(p1v[2]), "v"(p1v[3]));
        };

        const bool istail = (kv0 + KVB > Nn);
        #pragma unroll
        for (int ks = 0; ks < 2; ++ks) {
            unsigned pa[2][2], pb[2][2];
            if (!istail) {
                if (kv0 < nreg1) { qbody(2 * ks, pa, TrueC{}, FalseC{});  qbody(2 * ks + 1, pb, TrueC{}, FalseC{}); }
                else             { qbody(2 * ks, pa, FalseC{}, FalseC{}); qbody(2 * ks + 1, pb, FalseC{}, FalseC{}); }
            } else {
                qbody(2 * ks, pa, FalseC{}, TrueC{}); qbody(2 * ks + 1, pb, FalseC{}, TrueC{});
            }
            __builtin_amdgcn_s_setprio(1);
            #pragma unroll
            for (int hh = 0; hh < QH; hh++) {
                union { unsigned u[4]; short8 s; } pu;
                redist(pa[hh][0], pb[hh][0], pu.u[0], pu.u[2]);
                redist(pa[hh][1], pb[hh][1], pu.u[1], pu.u[3]);
                #pragma unroll
                for (int c2 = 0; c2 < 4; c2++) {
                    const int d = c2 * 16 + cl;
                    const int slot = ((ks << 2) + g) ^ (cl & 7);
                    const short8 vf = *(const short8*)&Vbuf[cur][hh][d * 64 + slot * 8];
                    o[hh][c2] = __builtin_amdgcn_mfma_f32_16x16x32_bf16(pu.s, vf, o[hh][c2], 0, 0, 0);
                }
            }
            __builtin_amdgcn_s_setprio(0);
        }
        cur ^= 1;
    }

    // ---- epilogue ----
    #pragma unroll
    for (int hh = 0; hh < QH; hh++) {
        float r = psum[hh];
        r += __shfl_xor(r, 16);
        r += __shfl_xor(r, 32);
        if (lane < 16) Rs[w][hh][lane] = r;
    }
    float4 rs0 = *(const float4*)&Rs[w][0][4 * g];
    float4 rs1 = *(const float4*)&Rs[w][1][4 * g];
    #pragma unroll
    for (int i = 0; i < 4; i++) {
        if (qi[i] < Nn) {
            #pragma unroll
            for (int hh = 0; hh < QH; hh++) {
                size_t rbase = (((size_t)sp * B + b) * NH + (h0 + hh)) * Nn + qi[i];
                #pragma unroll
                for (int c2 = 0; c2 < 4; c2++)
                    opart[rbase * HD + c2 * 16 + cl] = f2bf(o[hh][c2][i]);
                if (cl == 0) ppart[rbase] = hh ? rs1[i] : rs0[i];
            }
        }
    }
}

// ---------------- combine split-K partials, normalize, write Ob bf16 ----------------
__global__ __launch_bounds__(256) void attn_reduce(const short* __restrict__ opart,
        const float* __restrict__ ppart, short* __restrict__ Ob, int B, int Nn) {
    const int rows = B * NH * Nn;
    const int row = blockIdx.x * 4 + (threadIdx.x >> 6);
    if (row >= rows) return;
    const int d = threadIdx.x & 63;
    const int n = row % Nn;
    const int bh = row / Nn;
    const int h = bh % NH, b = bh / NH;
    const size_t stride = (size_t)B * NH * Nn;
    float o = 0.f, p = 0.f;
    #pragma unroll
    for (int s = 0; s < NSPLIT; s++) {
        o += bf2f(opart[((size_t)s * stride + row) * HD + d]);
        p += ppart[(size_t)s * stride + row];
    }
    Ob[((size_t)b * Nn + n) * DMODEL + h * HD + d] = f2bf(o / p);
}

extern "C" void kernel_launch(void* const* d_in, const int* in_sizes, int n_in,
                              void* d_out, int out_size, void* d_ws, size_t ws_size,
                              hipStream_t stream) {
    const float* x    = (const float*)d_in[0];
    const float* pos  = (const float*)d_in[1];
    const float* psz  = (const float*)d_in[2];
    const int*   nreg = (const int*)d_in[3];
    const float* ln1g = (const float*)d_in[4];
    const float* ln1b = (const float*)d_in[5];
    const float* wq   = (const float*)d_in[6];
    const float* bq   = (const float*)d_in[7];
    const float* wk   = (const float*)d_in[8];
    const float* bk   = (const float*)d_in[9];
    const float* wv   = (const float*)d_in[10];
    const float* bv   = (const float*)d_in[11];
    const float* wo   = (const float*)d_in[12];
    const float* bo   = (const float*)d_in[13];
    const float* qng  = (const float*)d_in[14];
    const float* qnb  = (const float*)d_in[15];
    const float* kng  = (const float*)d_in[16];
    const float* knb  = (const float*)d_in[17];
    const float* ln2g = (const float*)d_in[18];
    const float* ln2b = (const float*)d_in[19];
    const float* w1   = (const float*)d_in[20];
    const float* b1   = (const float*)d_in[21];
    const float* w2   = (const float*)d_in[22];
    const float* b2   = (const float*)d_in[23];

    const int B  = in_sizes[2];
    const int Nn = in_sizes[1] / (2 * B);
    const int M  = B * Nn;

    char* ws = (char*)d_ws;
    size_t off = 0;
    auto alloc = [&](size_t bytes) -> char* {
        char* p = ws + off;
        off += (bytes + 255) & ~(size_t)255;
        return p;
    };
    short* wt_qkv   = (short*)alloc((size_t)2304 * 768 * 2);
    short* wt_o     = (short*)alloc((size_t)768 * 768 * 2);
    short* wt_1     = (short*)alloc((size_t)3072 * 768 * 2);
    short* wt_2     = (short*)alloc((size_t)768 * 3072 * 2);
    float* bias_qkv = (float*)alloc(2304 * 4);
    short* xn       = (short*)alloc((size_t)M * 768 * 2);
    short* Qb       = (short*)alloc((size_t)M * 768 * 2);
    short* Kb       = (short*)alloc((size_t)M * 768 * 2);
    short* Vt       = (short*)alloc((size_t)B * NH * HD * NP * 2 + 4096);
    short* Ob       = (short*)alloc((size_t)M * 768 * 2);
    float* x1       = (float*)alloc((size_t)M * 768 * 4);
    short* xn2      = (short*)alloc((size_t)M * 768 * 2);
    short* hmid     = (short*)alloc((size_t)M * 3072 * 2);
    float* ppart    = (float*)alloc((size_t)NSPLIT * B * NH * Nn * 4);
    // opart (bf16) aliases hmid: NSPLIT*B*NH*Nn*64*2 = 12.6MB < 25.2MB; disjoint lifetimes
    short* opart    = hmid;

    dim3 blk(256);
    transpose_all<<<6912, blk, 0, stream>>>(wq, wk, wv, wo, w1, w2, wt_qkv, wt_o, wt_1, wt_2);
    concat_bias<<<9, blk, 0, stream>>>(bq, bk, bv, bias_qkv);

    const int MB64 = (M + 63) / 64;
    ln_rows<<<M, blk, 0, stream>>>(x, ln1g, ln1b, xn, M);
    gemm_qkv<<<18 * MB64, blk, 0, stream>>>(xn, wt_qkv, bias_qkv, qng, qnb, kng, knb,
                                            Qb, Kb, Vt, M, B, Nn);
    const int nqt = (Nn + 63) / 64;
    const int anwg = nqt * (NH / QH) * NSPLIT * B;
    attn_kernel<<<anwg, blk, 0, stream>>>(Qb, Kb, Vt, pos, psz, nreg, opart, ppart, B, Nn, anwg);
    attn_reduce<<<(B * NH * Nn + 3) / 4, blk, 0, stream>>>(opart, ppart, Ob, B, Nn);
    gemm_bt<1, 64, 64><<<12 * MB64, blk, 0, stream>>>(Ob, wt_o, bo, x, x1, M, 768, 768);
    ln_rows<<<M, blk, 0, stream>>>(x1, ln2g, ln2b, xn2, M);
    gemm_bt<2, 64, 128><<<24 * MB64, blk, 0, stream>>>(xn2, wt_1, b1, nullptr, hmid, M, 3072, 768);
    gemm_bt<1, 64, 64><<<12 * MB64, blk, 0, stream>>>(hmid, wt_2, b2, x1, (float*)d_out, M, 768, 3072);
}

// Round 15
// 249.605 us; speedup vs baseline: 1.0461x; 1.0461x over previous
//
#include <hip/hip_runtime.h>
#include <hip/hip_bf16.h>
#include <math.h>

typedef __attribute__((ext_vector_type(4))) float f32x4;
typedef __attribute__((ext_vector_type(8))) short short8;

#define DMODEL 768
#define NH 12
#define HD 64
#define DFF 3072
#define KVB 64
#define NSPLIT 3
#define QH 2
#define NP 1040   // padded Vt row stride

struct FalseC { static constexpr bool v = false; };
struct TrueC  { static constexpr bool v = true;  };

__device__ __forceinline__ short f2bf(float f) {
    union { float f; unsigned int u; } c; c.f = f;
    unsigned int r = c.u + 0x7FFFu + ((c.u >> 16) & 1u);
    return (short)(r >> 16);
}

__device__ __forceinline__ float bf2f(short s) {
    union { unsigned int u; float f; } c; c.u = ((unsigned int)(unsigned short)s) << 16;
    return c.f;
}

__device__ __forceinline__ void gload16(const void* g, void* l) {
    __builtin_amdgcn_global_load_lds((const __attribute__((address_space(1))) void*)g,
                                     (__attribute__((address_space(3))) void*)l, 16, 0, 0);
}

// bijective XCD-chunking swizzle (m204)
__device__ __forceinline__ int xcd_swz(int o, int nwg) {
    int q = nwg >> 3, r = nwg & 7, x = o & 7, i = o >> 3;
    return (x < r ? x * (q + 1) : r * (q + 1) + (x - r) * q) + i;
}

// ---------------- batched weight transpose + cast (all 6 weights in one launch) ----------------
__global__ __launch_bounds__(256) void transpose_all(
        const float* __restrict__ wq, const float* __restrict__ wk, const float* __restrict__ wv,
        const float* __restrict__ wo, const float* __restrict__ w1, const float* __restrict__ w2,
        short* __restrict__ wt_qkv, short* __restrict__ wt_o,
        short* __restrict__ wt_1, short* __restrict__ wt_2) {
    __shared__ float tile[32][33];
    int bid = blockIdx.x;
    const float* src; short* dst; int K, Nn, nx;
    if (bid < 2304) {                       // 4 square 768x768 weights, 576 blocks each
        int s = bid / 576; bid -= s * 576;
        src = (s == 0) ? wq : (s == 1) ? wk : (s == 2) ? wv : wo;
        dst = (s < 3) ? (wt_qkv + (size_t)s * 768 * 768) : wt_o;
        K = 768; Nn = 768; nx = 24;
    } else if (bid < 4608) {                // w1 [768][3072]
        bid -= 2304; src = w1; dst = wt_1; K = 768; Nn = 3072; nx = 96;
    } else {                                // w2 [3072][768]
        bid -= 4608; src = w2; dst = wt_2; K = 3072; Nn = 768; nx = 24;
    }
    const int n0 = (bid % nx) * 32, k0 = (bid / nx) * 32;
    const int tx = threadIdx.x & 31, ty = threadIdx.x >> 5;
    #pragma unroll
    for (int i = ty; i < 32; i += 8) {
        int k = k0 + i, n = n0 + tx;
        tile[i][tx] = (k < K && n < Nn) ? src[(size_t)k * Nn + n] : 0.f;
    }
    __syncthreads();
    #pragma unroll
    for (int i = ty; i < 32; i += 8) {
        int n = n0 + i, k = k0 + tx;
        if (n < Nn && k < K) dst[(size_t)n * K + k] = f2bf(tile[tx][i]);
    }
}

__global__ void concat_bias(const float* __restrict__ bq, const float* __restrict__ bk,
                            const float* __restrict__ bv, float* __restrict__ out) {
    int i = blockIdx.x * 256 + threadIdx.x;
    if (i < 2304) out[i] = (i < 768) ? bq[i] : (i < 1536 ? bk[i - 768] : bv[i - 1536]);
}

// ---------------- row LayerNorm over D=768, out bf16 ----------------
__global__ __launch_bounds__(256) void ln_rows(const float* __restrict__ x, const float* __restrict__ g,
                                               const float* __restrict__ bb, short* __restrict__ out, int M) {
    __shared__ float red[8];
    const int row = blockIdx.x;
    const int tid = threadIdx.x;
    const float* xr = x + (size_t)row * DMODEL;
    float v[3];
    #pragma unroll
    for (int j = 0; j < 3; j++) v[j] = xr[tid + j * 256];
    float s = v[0] + v[1] + v[2];
    #pragma unroll
    for (int mk = 32; mk; mk >>= 1) s += __shfl_xor(s, mk);
    if ((tid & 63) == 0) red[tid >> 6] = s;
    __syncthreads();
    const float mean = (red[0] + red[1] + red[2] + red[3]) * (1.0f / 768.0f);
    float sq = 0.f;
    #pragma unroll
    for (int j = 0; j < 3; j++) { float d = v[j] - mean; sq += d * d; }
    #pragma unroll
    for (int mk = 32; mk; mk >>= 1) sq += __shfl_xor(sq, mk);
    if ((tid & 63) == 0) red[4 + (tid >> 6)] = sq;
    __syncthreads();
    const float var = (red[4] + red[5] + red[6] + red[7]) * (1.0f / 768.0f);
    const float rstd = rsqrtf(var + 1e-5f);
    short* orow = out + (size_t)row * DMODEL;
    #pragma unroll
    for (int j = 0; j < 3; j++) {
        int col = tid + j * 256;
        orow[col] = f2bf((v[j] - mean) * rstd * g[col] + bb[col]);
    }
}

// ---------------- QKV GEMM with fused qk-norm + V-transpose epilogue (R7 single-buffer) ------
__global__ __launch_bounds__(256) void gemm_qkv(const short* __restrict__ A, const short* __restrict__ Bt,
        const float* __restrict__ bias,
        const float* __restrict__ qg, const float* __restrict__ qb2,
        const float* __restrict__ kg, const float* __restrict__ kb2,
        short* __restrict__ Qb, short* __restrict__ Kb, short* __restrict__ Vtp,
        int M, int B, int Nseq) {
    __shared__ short As[64 * 64];
    __shared__ short Bs[128 * 64];
    const int nbx = 18, nby = (M + 63) / 64;
    const int sid = xcd_swz(blockIdx.x, nbx * nby);
    const int n0 = (sid % nbx) * 128, m0 = (sid / nbx) * 64;
    const int tid = threadIdx.x, w = tid >> 6, lane = tid & 63, g = lane >> 4, cl = lane & 15;
    const int wm = w >> 1, wn = w & 1;
    f32x4 acc[2][4];
    #pragma unroll
    for (int a = 0; a < 2; a++)
        #pragma unroll
        for (int b2 = 0; b2 < 4; b2++) acc[a][b2] = (f32x4){0.f, 0.f, 0.f, 0.f};
    for (int kk = 0; kk < 768; kk += 64) {
        #pragma unroll
        for (int c = 0; c < 1536; c += 256) {
            int ci = c + tid;
            if (ci < 512) {
                int row = ci >> 3, p = ci & 7;
                int arow = m0 + row; if (arow >= M) arow = M - 1;
                gload16(A + (size_t)arow * 768 + kk + ((p ^ (row & 7)) << 3), &As[ci * 8]);
            } else {
                int c2 = ci - 512;
                int row = c2 >> 3, p = c2 & 7;
                gload16(Bt + (size_t)(n0 + row) * 768 + kk + ((p ^ (row & 7)) << 3), &Bs[c2 * 8]);
            }
        }
        __syncthreads();
        #pragma unroll
        for (int kh = 0; kh < 2; ++kh) {
            short8 af[2], bf[4];
            #pragma unroll
            for (int mi = 0; mi < 2; mi++) {
                int ra = wm * 32 + mi * 16 + cl;
                af[mi] = *(const short8*)&As[ra * 64 + ((((kh << 2) + g) ^ (ra & 7)) << 3)];
            }
            #pragma unroll
            for (int ni = 0; ni < 4; ni++) {
                int rb = wn * 64 + ni * 16 + cl;
                bf[ni] = *(const short8*)&Bs[rb * 64 + ((((kh << 2) + g) ^ (rb & 7)) << 3)];
            }
            #pragma unroll
            for (int mi = 0; mi < 2; mi++)
                #pragma unroll
                for (int ni = 0; ni < 4; ni++)
                    acc[mi][ni] = __builtin_amdgcn_mfma_f32_16x16x32_bf16(af[mi], bf[ni], acc[mi][ni], 0, 0, 0);
        }
        __syncthreads();
    }
    const int t = n0 / 768;
    const int h = (n0 - t * 768) / 64 + wn;
    const int b0 = m0 / Nseq, bnd = (b0 + 1) * Nseq;
    float bi[4];
    #pragma unroll
    for (int ni = 0; ni < 4; ni++) bi[ni] = bias[n0 + wn * 64 + ni * 16 + cl];
    if (t < 2) {
        const float* gp = (t == 0) ? qg : kg;
        const float* bp = (t == 0) ? qb2 : kb2;
        float gv[4], bv[4];
        #pragma unroll
        for (int ni = 0; ni < 4; ni++) { gv[ni] = gp[ni * 16 + cl]; bv[ni] = bp[ni * 16 + cl]; }
        short* out = (t == 0) ? Qb : Kb;
        #pragma unroll
        for (int mi = 0; mi < 2; mi++)
            #pragma unroll
            for (int r = 0; r < 4; r++) {
                int row = m0 + wm * 32 + mi * 16 + 4 * g + r;
                float v0 = acc[mi][0][r] + bi[0];
                float v1 = acc[mi][1][r] + bi[1];
                float v2 = acc[mi][2][r] + bi[2];
                float v3 = acc[mi][3][r] + bi[3];
                float sx = v0 + v1 + v2 + v3;
                float sxx = v0 * v0 + v1 * v1 + v2 * v2 + v3 * v3;
                #pragma unroll
                for (int mk = 8; mk; mk >>= 1) { sx += __shfl_xor(sx, mk); sxx += __shfl_xor(sxx, mk); }
                float mean = sx * (1.0f / 64.0f);
                float var = sxx * (1.0f / 64.0f) - mean * mean;
                float rstd = rsqrtf(var + 1e-5f);
                if (row < M) {
                    int bb = (row >= bnd) ? b0 + 1 : b0;
                    int n = row - bb * Nseq;
                    size_t base = (((size_t)bb * NH + h) * Nseq + n) * HD + cl;
                    out[base + 0]  = f2bf(fmaf((v0 - mean) * rstd, gv[0], bv[0]));
                    out[base + 16] = f2bf(fmaf((v1 - mean) * rstd, gv[1], bv[1]));
                    out[base + 32] = f2bf(fmaf((v2 - mean) * rstd, gv[2], bv[2]));
                    out[base + 48] = f2bf(fmaf((v3 - mean) * rstd, gv[3], bv[3]));
                }
            }
    } else {
        #pragma unroll
        for (int mi = 0; mi < 2; mi++)
            #pragma unroll
            for (int r = 0; r < 4; r++) {
                int row = m0 + wm * 32 + mi * 16 + 4 * g + r;
                if (row < M) {
                    int bb = (row >= bnd) ? b0 + 1 : b0;
                    int n = row - bb * Nseq;
                    size_t vb2 = ((size_t)bb * NH + h) * HD + cl;
                    #pragma unroll
                    for (int ni = 0; ni < 4; ni++)
                        Vtp[(vb2 + ni * 16) * NP + n] = f2bf(acc[mi][ni][r] + bi[ni]);
                }
            }
    }
}

// ---------------- GEMM (R7 single-buffer BK=64): C = A * Bt^T + epilogue ----------------
template<int EPI, int BM, int BN>
__global__ __launch_bounds__(256) void gemm_bt(const short* __restrict__ A, const short* __restrict__ Bt,
        const float* __restrict__ bias, const float* __restrict__ res, void* __restrict__ Cv,
        int M, int Nn, int K) {
    constexpr int RM = BM / 32, RN = BN / 32;
    __shared__ short As[BM * 64];
    __shared__ short Bs[BN * 64];
    const int nbx = Nn / BN, nby = (M + BM - 1) / BM;
    const int sid = xcd_swz(blockIdx.x, nbx * nby);
    const int n0 = (sid % nbx) * BN, m0 = (sid / nbx) * BM;
    const int tid = threadIdx.x, w = tid >> 6, lane = tid & 63, g = lane >> 4, cl = lane & 15;
    const int wm = w >> 1, wn = w & 1;
    f32x4 acc[RM][RN];
    #pragma unroll
    for (int a = 0; a < RM; a++)
        #pragma unroll
        for (int b2 = 0; b2 < RN; b2++) acc[a][b2] = (f32x4){0.f, 0.f, 0.f, 0.f};
    constexpr int CHA = BM * 8, CHT = (BM + BN) * 8;
    for (int kk = 0; kk < K; kk += 64) {
        #pragma unroll
        for (int c = 0; c < CHT; c += 256) {
            int ci = c + tid;
            if (ci < CHA) {
                int row = ci >> 3, p = ci & 7;
                int arow = m0 + row; if (arow >= M) arow = M - 1;
                gload16(A + (size_t)arow * K + kk + ((p ^ (row & 7)) << 3), &As[ci * 8]);
            } else {
                int c2 = ci - CHA;
                int row = c2 >> 3, p = c2 & 7;
                gload16(Bt + (size_t)(n0 + row) * K + kk + ((p ^ (row & 7)) << 3), &Bs[c2 * 8]);
            }
        }
        __syncthreads();
        #pragma unroll
        for (int kh = 0; kh < 2; ++kh) {
            short8 af[RM], bf[RN];
            #pragma unroll
            for (int mi = 0; mi < RM; mi++) {
                int ra = wm * (BM / 2) + mi * 16 + cl;
                af[mi] = *(const short8*)&As[ra * 64 + ((((kh << 2) + g) ^ (ra & 7)) << 3)];
            }
            #pragma unroll
            for (int ni = 0; ni < RN; ni++) {
                int rb = wn * (BN / 2) + ni * 16 + cl;
                bf[ni] = *(const short8*)&Bs[rb * 64 + ((((kh << 2) + g) ^ (rb & 7)) << 3)];
            }
            #pragma unroll
            for (int mi = 0; mi < RM; mi++)
                #pragma unroll
                for (int ni = 0; ni < RN; ni++)
                    acc[mi][ni] = __builtin_amdgcn_mfma_f32_16x16x32_bf16(af[mi], bf[ni], acc[mi][ni], 0, 0, 0);
        }
        __syncthreads();
    }
    #pragma unroll
    for (int ni = 0; ni < RN; ++ni) {
        int col = n0 + wn * (BN / 2) + ni * 16 + cl;
        float bi = bias[col];
        #pragma unroll
        for (int mi = 0; mi < RM; ++mi) {
            int rb = m0 + wm * (BM / 2) + mi * 16 + 4 * g;
            #pragma unroll
            for (int r = 0; r < 4; ++r) {
                int row = rb + r;
                if (row < M) {
                    float vv = acc[mi][ni][r] + bi;
                    if (EPI == 1) {
                        vv += res[(size_t)row * Nn + col];
                        ((float*)Cv)[(size_t)row * Nn + col] = vv;
                    } else {
                        float ge = 0.5f * vv * (1.0f + erff(vv * 0.70710678118654752f));
                        ((short*)Cv)[(size_t)row * Nn + col] = f2bf(ge);
                    }
                }
            }
        }
    }
}

// ---------------- flash attention (R13 measured best, 84.4us): swapped QK^T, 2 heads, x3 -----
__global__ __launch_bounds__(256, 3) void attn_kernel(
        const short* __restrict__ Qb, const short* __restrict__ Kb, const short* __restrict__ Vt,
        const float* __restrict__ pos, const float* __restrict__ psz, const int* __restrict__ nregp,
        short* __restrict__ opart, float* __restrict__ ppart, int B, int Nn, int nwg) {
    __shared__ short Vbuf[2][QH][4096];   // per head: [64 d][8 slots of 8 kv], slot^=(d&7)
    __shared__ short Pl[4][QH][16][68];   // stride 68: measured 0-conflict (R9/R10)
    __shared__ float Rs[4][QH][16];
    const int nqt = (Nn + 63) >> 6;
    const int sid = xcd_swz(blockIdx.x, nwg);
    const int qt = sid % nqt;
    const int rem = sid / nqt;
    const int nyy = (NH / QH) * NSPLIT;
    const int yy = rem % nyy;
    const int b = rem / nyy;
    const int h0 = (yy / NSPLIT) * QH, sp = yy % NSPLIT;
    const int tid = threadIdx.x, w = tid >> 6, lane = tid & 63, g = lane >> 4, cl = lane & 15;
    const int nreg1 = 1 + nregp[0];
    const float inv_ps = 1.0f / fmaxf(psz[b], 1e-6f);
    const float sc2 = 0.125f * 1.4426950408889634f;
    const size_t bq = (size_t)b * Nn;
    const float2* __restrict__ pos2 = (const float2*)pos;
    const int q0 = qt * 64 + w * 16;

    size_t bh[QH], vb[QH];
    short8 qa[QH][2];
    float sP[QH];
    int qr = q0 + cl; if (qr > Nn - 1) qr = Nn - 1;
    const float2 qp = pos2[bq + qr];
    const float keepq = (qr < nreg1) ? 0.f : 1.f;
    #pragma unroll
    for (int hh = 0; hh < QH; hh++) {
        int h = h0 + hh;
        bh[hh] = ((size_t)b * NH + h) * (size_t)Nn;
        vb[hh] = ((size_t)b * NH + h) * (size_t)(HD * NP);
        float slope = (h < 8) ? exp2f(-(float)(h + 1)) : exp2f(-0.5f - (float)(h - 8));
        sP[hh] = slope * inv_ps * 1.4426950408889634f * keepq;
        const short* qptr = Qb + (bh[hh] + qr) * HD;
        qa[hh][0] = *(const short8*)(qptr + 8 * g);
        qa[hh][1] = *(const short8*)(qptr + 32 + 8 * g);
    }

    int qi[4];
    #pragma unroll
    for (int i = 0; i < 4; i++) qi[i] = q0 + 4 * g + i;

    f32x4 o[QH][4];
    float psum[QH] = {0.f, 0.f};
    #pragma unroll
    for (int hh = 0; hh < QH; hh++)
        #pragma unroll
        for (int c2 = 0; c2 < 4; c2++) o[hh][c2] = (f32x4){0.f, 0.f, 0.f, 0.f};

    const int ktiles = (Nn + KVB - 1) / KVB;
    const int tps = (ktiles + NSPLIT - 1) / NSPLIT;
    const int t0 = sp * tps, t1 = min(ktiles, t0 + tps);

    auto stage = [&](int buf, int kt) {
        const int kv0 = kt * KVB;
        #pragma unroll
        for (int it = 0; it < 2 * QH; ++it) {
            int idx = it * 256 + tid;
            int hh = idx >> 9, rm = idx & 511;
            int d = rm >> 3, slot = rm & 7;
            int kvs = kv0 + ((slot ^ (d & 7)) << 3);
            gload16(Vt + vb[hh] + (size_t)d * NP + kvs, &Vbuf[buf][hh][rm * 8]);
        }
    };

    stage(0, t0);
    int cur = 0;
    for (int kt = t0; kt < t1; ++kt) {
        const int kv0 = kt * KVB;
        __syncthreads();                 // drains stage(kt)
        if (kt + 1 < t1) stage(cur ^ 1, kt + 1);

        // ---- swapped QK^T per 16-k quarter: lane holds P[k=4g+i][q=cl] ----
        auto qbody = [&](int qt2, auto mc, auto tc) {
            constexpr bool KMASK = decltype(mc)::v;
            constexpr bool TAIL  = decltype(tc)::v;
            const int kbase = kv0 + qt2 * 16;
            int krow = kbase + cl;
            if (TAIL) krow = min(krow, Nn - 1);
            const short* kp0 = Kb + (bh[0] + krow) * HD;
            const short* kp1 = Kb + (bh[1] + krow) * HD;
            const short8 k00 = *(const short8*)(kp0 + 8 * g);
            const short8 k01 = *(const short8*)(kp0 + 32 + 8 * g);
            const short8 k10 = *(const short8*)(kp1 + 8 * g);
            const short8 k11 = *(const short8*)(kp1 + 32 + 8 * g);
            f32x4 s0 = __builtin_amdgcn_mfma_f32_16x16x32_bf16(k00, qa[0][0], (f32x4){0.f,0.f,0.f,0.f}, 0, 0, 0);
            s0 = __builtin_amdgcn_mfma_f32_16x16x32_bf16(k01, qa[0][1], s0, 0, 0, 0);
            f32x4 s1 = __builtin_amdgcn_mfma_f32_16x16x32_bf16(k10, qa[1][0], (f32x4){0.f,0.f,0.f,0.f}, 0, 0, 0);
            s1 = __builtin_amdgcn_mfma_f32_16x16x32_bf16(k11, qa[1][1], s1, 0, 0, 0);
            const int kb4 = kbase + 4 * g;
            float p0v[4], p1v[4];
            #pragma unroll
            for (int i = 0; i < 4; i++) {
                int ki = kb4 + i;
                int kic = TAIL ? min(ki, Nn - 1) : ki;
                float2 kp2 = pos2[bq + kic];
                float dx = qp.x - kp2.x, dy = qp.y - kp2.y;
                float dist = sqrtf(fmaf(dx, dx, dy * dy));
                if (KMASK) dist *= (ki < nreg1) ? 0.f : 1.f;
                float e0 = fmaf(s0[i], sc2, -12.0f);
                e0 = fmaf(-sP[0], dist, e0);
                float p0 = exp2f(e0);
                float e1 = fmaf(s1[i], sc2, -12.0f);
                e1 = fmaf(-sP[1], dist, e1);
                float p1 = exp2f(e1);
                if (TAIL) { bool vl = ki < Nn; p0 = vl ? p0 : 0.f; p1 = vl ? p1 : 0.f; }
                psum[0] += p0; psum[1] += p1;
                p0v[i] = p0; p1v[i] = p1;
            }
            unsigned int w00, w01, w10, w11;
            asm("v_cvt_pk_bf16_f32 %0, %1, %2" : "=v"(w00) : "v"(p0v[0]), "v"(p0v[1]));
            asm("v_cvt_pk_bf16_f32 %0, %1, %2" : "=v"(w01) : "v"(p0v[2]), "v"(p0v[3]));
            asm("v_cvt_pk_bf16_f32 %0, %1, %2" : "=v"(w10) : "v"(p1v[0]), "v"(p1v[1]));
            asm("v_cvt_pk_bf16_f32 %0, %1, %2" : "=v"(w11) : "v"(p1v[2]), "v"(p1v[3]));
            *(unsigned int*)&Pl[w][0][cl][qt2 * 16 + 4 * g]     = w00;
            *(unsigned int*)&Pl[w][0][cl][qt2 * 16 + 4 * g + 2] = w01;
            *(unsigned int*)&Pl[w][1][cl][qt2 * 16 + 4 * g]     = w10;
            *(unsigned int*)&Pl[w][1][cl][qt2 * 16 + 4 * g + 2] = w11;
        };

        const bool istail = (kv0 + KVB > Nn);
        if (!istail) {
            if (kv0 < nreg1) {
                qbody(0, TrueC{}, FalseC{}); qbody(1, TrueC{}, FalseC{});
                qbody(2, TrueC{}, FalseC{}); qbody(3, TrueC{}, FalseC{});
            } else {
                qbody(0, FalseC{}, FalseC{}); qbody(1, FalseC{}, FalseC{});
                qbody(2, FalseC{}, FalseC{}); qbody(3, FalseC{}, FalseC{});
            }
        } else {
            qbody(0, FalseC{}, TrueC{}); qbody(1, FalseC{}, TrueC{});
            qbody(2, FalseC{}, TrueC{}); qbody(3, FalseC{}, TrueC{});
        }

        // ---- PV ----
        __builtin_amdgcn_s_setprio(1);
        #pragma unroll
        for (int hh = 0; hh < QH; hh++) {
            #pragma unroll
            for (int ks = 0; ks < 2; ++ks) {
                const short8 pf = *(const short8*)&Pl[w][hh][cl][ks * 32 + 8 * g];
                #pragma unroll
                for (int c2 = 0; c2 < 4; c2++) {
                    const int d = c2 * 16 + cl;
                    const int slot = ((ks << 2) + g) ^ (cl & 7);
                    const short8 vf = *(const short8*)&Vbuf[cur][hh][d * 64 + slot * 8];
                    o[hh][c2] = __builtin_amdgcn_mfma_f32_16x16x32_bf16(pf, vf, o[hh][c2], 0, 0, 0);
                }
            }
        }
        __builtin_amdgcn_s_setprio(0);
        cur ^= 1;
    }

    // ---- epilogue ----
    #pragma unroll
    for (int hh = 0; hh < QH; hh++) {
        float r = psum[hh];
        r += __shfl_xor(r, 16);
        r += __shfl_xor(r, 32);
        if (lane < 16) Rs[w][hh][lane] = r;
    }
    float4 rs0 = *(const float4*)&Rs[w][0][4 * g];
    float4 rs1 = *(const float4*)&Rs[w][1][4 * g];
    #pragma unroll
    for (int i = 0; i < 4; i++) {
        if (qi[i] < Nn) {
            #pragma unroll
            for (int hh = 0; hh < QH; hh++) {
                size_t rbase = (((size_t)sp * B + b) * NH + (h0 + hh)) * Nn + qi[i];
                #pragma unroll
                for (int c2 = 0; c2 < 4; c2++)
                    opart[rbase * HD + c2 * 16 + cl] = f2bf(o[hh][c2][i]);
                if (cl == 0) ppart[rbase] = hh ? rs1[i] : rs0[i];
            }
        }
    }
}

// ---------------- combine split-K partials, normalize, write Ob bf16 ----------------
__global__ __launch_bounds__(256) void attn_reduce(const short* __restrict__ opart,
        const float* __restrict__ ppart, short* __restrict__ Ob, int B, int Nn) {
    const int rows = B * NH * Nn;
    const int row = blockIdx.x * 4 + (threadIdx.x >> 6);
    if (row >= rows) return;
    const int d = threadIdx.x & 63;
    const int n = row % Nn;
    const int bh = row / Nn;
    const int h = bh % NH, b = bh / NH;
    const size_t stride = (size_t)B * NH * Nn;
    float o = 0.f, p = 0.f;
    #pragma unroll
    for (int s = 0; s < NSPLIT; s++) {
        o += bf2f(opart[((size_t)s * stride + row) * HD + d]);
        p += ppart[(size_t)s * stride + row];
    }
    Ob[((size_t)b * Nn + n) * DMODEL + h * HD + d] = f2bf(o / p);
}

extern "C" void kernel_launch(void* const* d_in, const int* in_sizes, int n_in,
                              void* d_out, int out_size, void* d_ws, size_t ws_size,
                              hipStream_t stream) {
    const float* x    = (const float*)d_in[0];
    const float* pos  = (const float*)d_in[1];
    const float* psz  = (const float*)d_in[2];
    const int*   nreg = (const int*)d_in[3];
    const float* ln1g = (const float*)d_in[4];
    const float* ln1b = (const float*)d_in[5];
    const float* wq   = (const float*)d_in[6];
    const float* bq   = (const float*)d_in[7];
    const float* wk   = (const float*)d_in[8];
    const float* bk   = (const float*)d_in[9];
    const float* wv   = (const float*)d_in[10];
    const float* bv   = (const float*)d_in[11];
    const float* wo   = (const float*)d_in[12];
    const float* bo   = (const float*)d_in[13];
    const float* qng  = (const float*)d_in[14];
    const float* qnb  = (const float*)d_in[15];
    const float* kng  = (const float*)d_in[16];
    const float* knb  = (const float*)d_in[17];
    const float* ln2g = (const float*)d_in[18];
    const float* ln2b = (const float*)d_in[19];
    const float* w1   = (const float*)d_in[20];
    const float* b1   = (const float*)d_in[21];
    const float* w2   = (const float*)d_in[22];
    const float* b2   = (const float*)d_in[23];

    const int B  = in_sizes[2];
    const int Nn = in_sizes[1] / (2 * B);
    const int M  = B * Nn;

    char* ws = (char*)d_ws;
    size_t off = 0;
    auto alloc = [&](size_t bytes) -> char* {
        char* p = ws + off;
        off += (bytes + 255) & ~(size_t)255;
        return p;
    };
    short* wt_qkv   = (short*)alloc((size_t)2304 * 768 * 2);
    short* wt_o     = (short*)alloc((size_t)768 * 768 * 2);
    short* wt_1     = (short*)alloc((size_t)3072 * 768 * 2);
    short* wt_2     = (short*)alloc((size_t)768 * 3072 * 2);
    float* bias_qkv = (float*)alloc(2304 * 4);
    short* xn       = (short*)alloc((size_t)M * 768 * 2);
    short* Qb       = (short*)alloc((size_t)M * 768 * 2);
    short* Kb       = (short*)alloc((size_t)M * 768 * 2);
    short* Vt       = (short*)alloc((size_t)B * NH * HD * NP * 2 + 4096);
    short* Ob       = (short*)alloc((size_t)M * 768 * 2);
    float* x1       = (float*)alloc((size_t)M * 768 * 4);
    short* xn2      = (short*)alloc((size_t)M * 768 * 2);
    short* hmid     = (short*)alloc((size_t)M * 3072 * 2);
    float* ppart    = (float*)alloc((size_t)NSPLIT * B * NH * Nn * 4);
    // opart (bf16) aliases hmid: NSPLIT*B*NH*Nn*64*2 = 18.9MB < M*6144B = 25.2MB; disjoint lifetimes
    short* opart    = hmid;

    dim3 blk(256);
    transpose_all<<<6912, blk, 0, stream>>>(wq, wk, wv, wo, w1, w2, wt_qkv, wt_o, wt_1, wt_2);
    concat_bias<<<9, blk, 0, stream>>>(bq, bk, bv, bias_qkv);

    const int MB64 = (M + 63) / 64;
    ln_rows<<<M, blk, 0, stream>>>(x, ln1g, ln1b, xn, M);
    gemm_qkv<<<18 * MB64, blk, 0, stream>>>(xn, wt_qkv, bias_qkv, qng, qnb, kng, knb,
                                            Qb, Kb, Vt, M, B, Nn);
    const int nqt = (Nn + 63) / 64;
    const int anwg = nqt * (NH / QH) * NSPLIT * B;
    attn_kernel<<<anwg, blk, 0, stream>>>(Qb, Kb, Vt, pos, psz, nreg, opart, ppart, B, Nn, anwg);
    attn_reduce<<<(B * NH * Nn + 3) / 4, blk, 0, stream>>>(opart, ppart, Ob, B, Nn);
    gemm_bt<1, 64, 64><<<12 * MB64, blk, 0, stream>>>(Ob, wt_o, bo, x, x1, M, 768, 768);
    ln_rows<<<M, blk, 0, stream>>>(x1, ln2g, ln2b, xn2, M);
    gemm_bt<2, 64, 128><<<24 * MB64, blk, 0, stream>>>(xn2, wt_1, b1, nullptr, hmid, M, 3072, 768);
    gemm_bt<1, 64, 64><<<12 * MB64, blk, 0, stream>>>(hmid, wt_2, b2, x1, (float*)d_out, M, 768, 3072);
}